// Round 3
// baseline (44.597 us; speedup 1.0000x reference)
//
#include <hip/hip_runtime.h>
#include <math.h>

#define BLOCK 512
#define WPB 8          // waves per block
#define NGRID 1000
#define WSTRIDE 68     // padded LDS row stride (floats): 16B-aligned, conflict-free
#define HPAD 68

// Dense 64->64 for 2 rows per wave. Lane j owns output unit j.
// Weights transposed in LDS with row stride 68 floats: lane j reads
// wt[j*68 + 4*i4 ..] -> bank (4j + i) % 32 varies with j -> conflict-free.
// h reads are wave-uniform addresses -> LDS broadcast (free).
// In-place h update safe: wave64 lockstep, LDS ops in order per wave.
__device__ __forceinline__ void dense64x2(const float* __restrict__ wt,
                                          const float* __restrict__ bias,
                                          float (*h)[HPAD], int j)
{
    const float* wrow = wt + j * WSTRIDE;
    float ac0 = bias[j];
    float ac1 = ac0;
    #pragma unroll
    for (int i4 = 0; i4 < 16; ++i4) {
        const float4 wv = *(const float4*)(wrow + (i4 << 2));
        const float4 h0 = *(const float4*)(&h[0][i4 << 2]);
        const float4 h1 = *(const float4*)(&h[1][i4 << 2]);
        ac0 = fmaf(h0.x, wv.x, ac0); ac0 = fmaf(h0.y, wv.y, ac0);
        ac0 = fmaf(h0.z, wv.z, ac0); ac0 = fmaf(h0.w, wv.w, ac0);
        ac1 = fmaf(h1.x, wv.x, ac1); ac1 = fmaf(h1.y, wv.y, ac1);
        ac1 = fmaf(h1.z, wv.z, ac1); ac1 = fmaf(h1.w, wv.w, ac1);
    }
    h[0][j] = fmaxf(ac0, 0.0f);
    h[1][j] = fmaxf(ac1, 0.0f);
}

__global__ __launch_bounds__(BLOCK, 6) void ph_kernel(
    const float* __restrict__ x,
    const float* __restrict__ W1, const float* __restrict__ b1,
    const float* __restrict__ W2, const float* __restrict__ b2,
    const float* __restrict__ W3, const float* __restrict__ b3,
    const float* __restrict__ W4, const float* __restrict__ b4,
    const float* __restrict__ kin,
    float* __restrict__ out, int B)
{
    __shared__ __attribute__((aligned(16))) float sW2t[64*WSTRIDE];
    __shared__ __attribute__((aligned(16))) float sW3t[64*WSTRIDE];
    __shared__ __attribute__((aligned(16))) float sW4t[6*WSTRIDE];
    __shared__ __attribute__((aligned(16))) float sH[WPB][2][HPAD];
    __shared__ float sW1[5*64];
    __shared__ float sB1[64], sB2[64], sB3[64], sB4[8];
    __shared__ float sLat[WPB][2][8];

    const int tid = threadIdx.x;

    // ---- stage weights (transposed, pad-68 rows) ----
    for (int l = tid; l < 5*64; l += BLOCK) sW1[l] = W1[l];
    for (int l = tid; l < 64*64; l += BLOCK) {
        const int i = l >> 6, j = l & 63;
        sW2t[j*WSTRIDE + i] = W2[l];
        sW3t[j*WSTRIDE + i] = W3[l];
    }
    for (int l = tid; l < 64*6; l += BLOCK) {
        const int i = l / 6, u = l - 6*i;
        sW4t[u*WSTRIDE + i] = W4[l];
    }
    if (tid < 64) { sB1[tid] = b1[tid]; sB2[tid] = b2[tid]; sB3[tid] = b3[tid]; }
    if (tid < 8)  sB4[tid] = (tid < 6) ? b4[tid] : 0.0f;
    __syncthreads();   // the only block-wide barrier

    const int lane = tid & 63;
    const int widx = tid >> 6;
    const int half = lane >> 5;       // 0: row A, 1: row B
    const int la   = lane & 31;
    const int nw   = gridDim.x * WPB;
    const int w    = blockIdx.x * WPB + widx;

    const float i00 = kin[0], i01 = kin[1], i02 = kin[2];
    // Tafel coefficients, exact ref op order: ks = (-alpha)*F
    const float ks0 = (-kin[3]) * 96485.33f;
    const float ks1 = (-kin[4]) * 96485.33f;
    const float ks2 = (-kin[5]) * 96485.33f;
    const float stepV = 1.25f / 999.0f;

    float (*h)[HPAD] = sH[widx];
    const int j = lane;

    for (int row0 = w*2; row0 < B; row0 += nw*2) {
        // ---- layer 1: 5 -> 64 (x reads wave-uniform -> scalar loads) ----
        #pragma unroll
        for (int r = 0; r < 2; ++r) {
            const int row = (row0 + r < B) ? (row0 + r) : (B - 1);
            float acc = sB1[j];
            #pragma unroll
            for (int i = 0; i < 5; ++i)
                acc = fmaf(x[row*5 + i], sW1[(i << 6) + j], acc);
            h[r][j] = fmaxf(acc, 0.0f);
        }

        // ---- layers 2,3: 64 -> 64 ----
        dense64x2(sW2t, sB2, h, j);
        dense64x2(sW3t, sB3, h, j);

        // ---- layer 4: 64 -> 6, lanes 0..11 = (r = lane&1, u = lane>>1) ----
        // sequential i ascending via b128 x,y,z,w: same order as scalar loop.
        if (lane < 12) {
            const int r = lane & 1, u = lane >> 1;
            const float* wrow = sW4t + u * WSTRIDE;
            float acc = sB4[u];
            #pragma unroll
            for (int i4 = 0; i4 < 16; ++i4) {
                const float4 wv = *(const float4*)(wrow + (i4 << 2));
                const float4 hv = *(const float4*)(&h[r][i4 << 2]);
                acc = fmaf(hv.x, wv.x, acc); acc = fmaf(hv.y, wv.y, acc);
                acc = fmaf(hv.z, wv.z, acc); acc = fmaf(hv.w, wv.w, acc);
            }
            sLat[widx][r][u] = acc;
        }

        const int row = row0 + half;
        const bool act = (row < B);

        // ---- physics: ONE issue for both rows (lanes 0 and 32) ----
        float c0v = 0.0f, c1v = 0.0f, c2v = 0.0f, l0v = 0.0f, l1v = 0.0f;
        if (la == 0) {
            const float* plat = sLat[widx][half];
            const float lat0 = plat[0], lat1 = plat[1], lat2 = plat[2];
            const float lat3 = plat[3], lat4 = plat[4], lat5 = plat[5];
            const int rowc = act ? row : (B - 1);
            const float rr   = 4e-8f * expf(lat0);
            const float epsv = 1.0f / (1.0f + expf(-lat1));
            const float zlt  = x[rowc*5 + 3];
            const float Lf   = zlt / (1.0f - epsv);
            const float Kdl  = expf(lat2);
            const float z0 = 2.0f*lat3, z1 = 2.0f*lat4, z2 = 2.0f*lat5;
            const float mz = fmaxf(z0, fmaxf(z1, z2));
            const float p0 = expf(z0 - mz), p1 = expf(z1 - mz), p2 = expf(z2 - mz);
            const float ps = p0 + p1 + p2;
            const float th0 = p0/ps, th1 = p1/ps, th2 = p2/ps;
            const float gdl   = (Kdl * 1.91e-9f) * powf(epsv, 1.5f) / rr;
            const float asurf = (3.0f * (1.0f - epsv)) * Lf / rr;
            c0v = (i00*th0)*asurf; c1v = (i01*th1)*asurf; c2v = (i02*th2)*asurf;
            const float il0 = (((2.0f*96485.33f)*34.0f)*gdl)*0.1f;
            const float il1 = (((12.0f*96485.33f)*34.0f)*gdl)*0.1f;
            l0v = 1.0f/il0; l1v = 1.0f/il1;
        }
        // broadcast row constants within each half (bit-exact)
        const int src = half << 5;
        const float c0    = __shfl(c0v, src, 64);
        const float c1    = __shfl(c1v, src, 64);
        const float c2    = __shfl(c2v, src, 64);
        const float invl0 = __shfl(l0v, src, 64);
        const float invl1 = __shfl(l1v, src, 64);

        // exact per-point eval, tafel on the fly (identical expr to table build)
        auto evaltot = [&](int v) -> float {
            const float V = -1.25f + stepV * (float)v;
            const float t0 = expf((ks0 * (V - (-0.11f))) / 2478.8191f);
            const float t1 = expf((ks1 * (V - 0.08f))    / 2478.8191f);
            const float t2 = expf((ks2 * (V - 0.0f))     / 2478.8191f);
            const float ie0 = 1.0f / (1.0f/(c0*t0) + invl0);
            const float ie1 = 1.0f / (1.0f/(c1*t1) + invl1);
            const float ie2 = 1.0f / (1.0f/(c2*t2));   // i_lim[2] = inf
            return ie0 + ie1 + ie2;
        };

        // coarse: 32 points stride 32 per half; i_tot weakly decreasing in v
        const int vc = la << 5;                 // 0..992
        const float totc = evaltot(vc);
        float bd = fabsf(totc - 200.0f);
        int bidx = vc;

        const unsigned long long mall = __ballot(totc >= 200.0f);
        const unsigned int m32 = (unsigned int)(mall >> (half << 5));
        const int kstar = m32 ? (31 - __builtin_clz(m32)) : 0;
        const int base = kstar << 5;

        // fine: 32 points (base, base+32]; coarse candidates cover the rest
        {
            int vf = base + 1 + la;
            if (vf > NGRID-1) vf = NGRID-1;
            const float totf = evaltot(vf);
            const float df = fabsf(totf - 200.0f);
            if (df < bd || (df == bd && vf < bidx)) { bd = df; bidx = vf; }
        }

        // lexicographic (d, idx) butterfly within each 32-lane half
        #pragma unroll
        for (int off = 16; off; off >>= 1) {
            const float od = __shfl_xor(bd, off, 64);
            const int   oi = __shfl_xor(bidx, off, 64);
            if (od < bd || (od == bd && oi < bidx)) { bd = od; bidx = oi; }
        }

        // ---- select + FE (exact) ----
        {
            const float V = -1.25f + stepV * (float)bidx;
            const float t0 = expf((ks0 * (V - (-0.11f))) / 2478.8191f);
            const float t1 = expf((ks1 * (V - 0.08f))    / 2478.8191f);
            const float t2 = expf((ks2 * (V - 0.0f))     / 2478.8191f);
            const float ie0 = 1.0f / (1.0f/(c0*t0) + invl0);
            const float ie1 = 1.0f / (1.0f/(c1*t1) + invl1);
            const float ie2 = 1.0f / (1.0f/(c2*t2));
            const float itsel = ie0 + ie1 + ie2;
            if (act && la < 2) {
                out[row*2 + la] = (la == 0) ? (ie1/itsel) : (ie0/itsel);
            }
        }
    }
}

extern "C" void kernel_launch(void* const* d_in, const int* in_sizes, int n_in,
                              void* d_out, int out_size, void* d_ws, size_t ws_size,
                              hipStream_t stream) {
    const float* x   = (const float*)d_in[0];
    const float* W1  = (const float*)d_in[1];
    const float* b1  = (const float*)d_in[2];
    const float* W2  = (const float*)d_in[3];
    const float* b2  = (const float*)d_in[4];
    const float* W3  = (const float*)d_in[5];
    const float* b3  = (const float*)d_in[6];
    const float* W4  = (const float*)d_in[7];
    const float* b4  = (const float*)d_in[8];
    const float* kin = (const float*)d_in[9];
    float* out = (float*)d_out;
    const int B = in_sizes[0] / 5;

    // 16 rows per block (8 waves x 2 rows): B=16384 -> 1024 blocks.
    // ~42 KB LDS -> 3 resident blocks/CU (24 waves/CU), 4 blocks per CU total.
    const int grid = (B + WPB*2 - 1) / (WPB*2);
    ph_kernel<<<grid, BLOCK, 0, stream>>>(x, W1, b1, W2, b2, W3, b3, W4, b4, kin, out, B);
}

// Round 4
// 21.887 us; speedup vs baseline: 2.0376x; 2.0376x over previous
//
#include <hip/hip_runtime.h>
#include <math.h>

#define BLOCK 512
#define WPB 8          // waves per block
#define NGRID 1000
#define HPAD 68        // h row stride (floats), 16B-aligned
#define W4S 68         // sW4t row stride

// Dense 64->64 for 4 rows per wave. Lane j owns output unit j.
// Weights transposed + XOR-swizzled in 16B granules: storage granule
// g of row j holds source granule (g ^ (j&7)). Read of (i4 ^ swz)
// returns source granule i4 -> accumulation order is i-ascending
// (bitwise identical to the scalar loop). 64 lanes x b128 = 1 KB per
// access = 8-cycle LDS floor; the 8-lane/4-bank grouping achieves it.
// h reads are wave-uniform -> broadcast. In-place h update safe:
// wave64 lockstep, per-wave LDS ordering.
__device__ __forceinline__ void dense64(const float* __restrict__ wt,
                                        const float* __restrict__ bias,
                                        float (*h)[HPAD], int j)
{
    const int swz = j & 7;
    const float* wrow = wt + (j << 6);
    float ac0 = bias[j];
    float ac1 = ac0, ac2 = ac0, ac3 = ac0;
    #pragma unroll
    for (int i4 = 0; i4 < 16; ++i4) {
        const float4 wv = *(const float4*)(wrow + ((i4 ^ swz) << 2));
        const float4 h0 = *(const float4*)(&h[0][i4 << 2]);
        const float4 h1 = *(const float4*)(&h[1][i4 << 2]);
        const float4 h2 = *(const float4*)(&h[2][i4 << 2]);
        const float4 h3 = *(const float4*)(&h[3][i4 << 2]);
        ac0 = fmaf(h0.x, wv.x, ac0); ac0 = fmaf(h0.y, wv.y, ac0);
        ac0 = fmaf(h0.z, wv.z, ac0); ac0 = fmaf(h0.w, wv.w, ac0);
        ac1 = fmaf(h1.x, wv.x, ac1); ac1 = fmaf(h1.y, wv.y, ac1);
        ac1 = fmaf(h1.z, wv.z, ac1); ac1 = fmaf(h1.w, wv.w, ac1);
        ac2 = fmaf(h2.x, wv.x, ac2); ac2 = fmaf(h2.y, wv.y, ac2);
        ac2 = fmaf(h2.z, wv.z, ac2); ac2 = fmaf(h2.w, wv.w, ac2);
        ac3 = fmaf(h3.x, wv.x, ac3); ac3 = fmaf(h3.y, wv.y, ac3);
        ac3 = fmaf(h3.z, wv.z, ac3); ac3 = fmaf(h3.w, wv.w, ac3);
    }
    h[0][j] = fmaxf(ac0, 0.0f);
    h[1][j] = fmaxf(ac1, 0.0f);
    h[2][j] = fmaxf(ac2, 0.0f);
    h[3][j] = fmaxf(ac3, 0.0f);
}

__global__ __launch_bounds__(BLOCK) void ph_kernel(
    const float* __restrict__ x,
    const float* __restrict__ W1, const float* __restrict__ b1,
    const float* __restrict__ W2, const float* __restrict__ b2,
    const float* __restrict__ W3, const float* __restrict__ b3,
    const float* __restrict__ W4, const float* __restrict__ b4,
    const float* __restrict__ kin,
    float* __restrict__ out, int B)
{
    __shared__ __attribute__((aligned(16))) float sW2t[64*64];
    __shared__ __attribute__((aligned(16))) float sW3t[64*64];
    __shared__ __attribute__((aligned(16))) float sW4t[6*W4S];
    __shared__ __attribute__((aligned(16))) float sH[WPB][4][HPAD];
    __shared__ float sW1[5*64];
    __shared__ float sB1[64], sB2[64], sB3[64], sB4[8];
    __shared__ float sLat[WPB][4][8];

    const int tid = threadIdx.x;

    // ---- stage weights (W2/W3 transposed + XOR-swizzled 16B granules) ----
    for (int l = tid; l < 5*64; l += BLOCK) sW1[l] = W1[l];
    for (int l = tid; l < 64*64; l += BLOCK) {
        const int i = l >> 6, j = l & 63;
        const int dst = (j << 6) + ((((i >> 2) ^ (j & 7)) << 2) | (i & 3));
        sW2t[dst] = W2[l];
        sW3t[dst] = W3[l];
    }
    for (int l = tid; l < 64*6; l += BLOCK) {
        const int i = l / 6, u = l - 6*i;
        sW4t[u*W4S + i] = W4[l];
    }
    if (tid < 64) { sB1[tid] = b1[tid]; sB2[tid] = b2[tid]; sB3[tid] = b3[tid]; }
    if (tid < 8)  sB4[tid] = (tid < 6) ? b4[tid] : 0.0f;
    __syncthreads();   // the only block-wide barrier

    const int lane = tid & 63;
    const int widx = tid >> 6;
    const int half = lane >> 5;
    const int la   = lane & 31;
    const int w    = blockIdx.x * WPB + widx;

    const float i00 = kin[0], i01 = kin[1], i02 = kin[2];
    // Tafel coefficients, exact ref op order: ks = (-alpha)*F
    const float ks0 = (-kin[3]) * 96485.33f;
    const float ks1 = (-kin[4]) * 96485.33f;
    const float ks2 = (-kin[5]) * 96485.33f;
    const float stepV = 1.25f / 999.0f;

    float (*h)[HPAD] = sH[widx];
    const int j = lane;
    const int row0 = w * 4;

    // ---- layer 1: 5 -> 64 (x reads wave-uniform -> scalar loads) ----
    #pragma unroll
    for (int r = 0; r < 4; ++r) {
        const int row = (row0 + r < B) ? (row0 + r) : (B - 1);
        float acc = sB1[j];
        #pragma unroll
        for (int i = 0; i < 5; ++i)
            acc = fmaf(x[row*5 + i], sW1[(i << 6) + j], acc);
        h[r][j] = fmaxf(acc, 0.0f);
    }

    // ---- layers 2,3: 64 -> 64 ----
    dense64(sW2t, sB2, h, j);
    dense64(sW3t, sB3, h, j);

    // ---- layer 4: 64 -> 6, lanes 0..23 = (r = lane&3, u = lane>>2) ----
    // b128 x,y,z,w ascending i: same accumulation order as scalar loop.
    if (lane < 24) {
        const int r = lane & 3, u = lane >> 2;
        const float* wrow = sW4t + u * W4S;
        float acc = sB4[u];
        #pragma unroll
        for (int i4 = 0; i4 < 16; ++i4) {
            const float4 wv = *(const float4*)(wrow + (i4 << 2));
            const float4 hv = *(const float4*)(&h[r][i4 << 2]);
            acc = fmaf(hv.x, wv.x, acc); acc = fmaf(hv.y, wv.y, acc);
            acc = fmaf(hv.z, wv.z, acc); acc = fmaf(hv.w, wv.w, acc);
        }
        sLat[widx][r][u] = acc;
    }

    // ---- physics: lanes {0,16,32,48} each run one row's chain ----
    float c0v = 0.0f, c1v = 0.0f, c2v = 0.0f, l0v = 0.0f, l1v = 0.0f;
    if ((lane & 15) == 0) {
        const int r = lane >> 4;
        const int row = (row0 + r < B) ? (row0 + r) : (B - 1);
        const float* plat = sLat[widx][r];
        const float lat0 = plat[0], lat1 = plat[1], lat2 = plat[2];
        const float lat3 = plat[3], lat4 = plat[4], lat5 = plat[5];
        const float rr   = 4e-8f * expf(lat0);
        const float epsv = 1.0f / (1.0f + expf(-lat1));
        const float zlt  = x[row*5 + 3];
        const float Lf   = zlt / (1.0f - epsv);
        const float Kdl  = expf(lat2);
        const float z0 = 2.0f*lat3, z1 = 2.0f*lat4, z2 = 2.0f*lat5;
        const float mz = fmaxf(z0, fmaxf(z1, z2));
        const float p0 = expf(z0 - mz), p1 = expf(z1 - mz), p2 = expf(z2 - mz);
        const float ps = p0 + p1 + p2;
        const float th0 = p0/ps, th1 = p1/ps, th2 = p2/ps;
        const float gdl   = (Kdl * 1.91e-9f) * powf(epsv, 1.5f) / rr;
        const float asurf = (3.0f * (1.0f - epsv)) * Lf / rr;
        c0v = (i00*th0)*asurf; c1v = (i01*th1)*asurf; c2v = (i02*th2)*asurf;
        const float il0 = (((2.0f*96485.33f)*34.0f)*gdl)*0.1f;
        const float il1 = (((12.0f*96485.33f)*34.0f)*gdl)*0.1f;
        l0v = 1.0f/il0; l1v = 1.0f/il1;
    }

    // ---- two scan passes: pass p handles rows {2p, 2p+1} in 32-lane halves ----
    #pragma unroll
    for (int p = 0; p < 2; ++p) {
        const int r   = (p << 1) + half;
        const int row = row0 + r;
        const bool act = (row < B);
        const int src = r << 4;            // lane holding this row's constants
        const float c0    = __shfl(c0v, src, 64);
        const float c1    = __shfl(c1v, src, 64);
        const float c2    = __shfl(c2v, src, 64);
        const float invl0 = __shfl(l0v, src, 64);
        const float invl1 = __shfl(l1v, src, 64);

        // exact per-point eval, tafel on the fly (identical expr/op order)
        auto evaltot = [&](int v) -> float {
            const float V = -1.25f + stepV * (float)v;
            const float t0 = expf((ks0 * (V - (-0.11f))) / 2478.8191f);
            const float t1 = expf((ks1 * (V - 0.08f))    / 2478.8191f);
            const float t2 = expf((ks2 * (V - 0.0f))     / 2478.8191f);
            const float ie0 = 1.0f / (1.0f/(c0*t0) + invl0);
            const float ie1 = 1.0f / (1.0f/(c1*t1) + invl1);
            const float ie2 = 1.0f / (1.0f/(c2*t2));   // i_lim[2] = inf
            return ie0 + ie1 + ie2;
        };

        // coarse: 32 points stride 32; i_tot weakly decreasing in v
        const int vc = la << 5;            // 0..992
        const float totc = evaltot(vc);
        float bd = fabsf(totc - 200.0f);
        int bidx = vc;

        const unsigned long long mall = __ballot(totc >= 200.0f);
        const unsigned int m32 = (unsigned int)(mall >> (half << 5));
        const int kstar = m32 ? (31 - __builtin_clz(m32)) : 0;
        const int base = kstar << 5;

        // fine: 32 points (base, base+32]; coarse candidates cover the rest
        {
            int vf = base + 1 + la;
            if (vf > NGRID-1) vf = NGRID-1;
            const float totf = evaltot(vf);
            const float df = fabsf(totf - 200.0f);
            if (df < bd || (df == bd && vf < bidx)) { bd = df; bidx = vf; }
        }

        // lexicographic (d, idx) butterfly within each 32-lane half
        #pragma unroll
        for (int off = 16; off; off >>= 1) {
            const float od = __shfl_xor(bd, off, 64);
            const int   oi = __shfl_xor(bidx, off, 64);
            if (od < bd || (od == bd && oi < bidx)) { bd = od; bidx = oi; }
        }

        // ---- select + FE (exact) ----
        const float V = -1.25f + stepV * (float)bidx;
        const float t0 = expf((ks0 * (V - (-0.11f))) / 2478.8191f);
        const float t1 = expf((ks1 * (V - 0.08f))    / 2478.8191f);
        const float t2 = expf((ks2 * (V - 0.0f))     / 2478.8191f);
        const float ie0 = 1.0f / (1.0f/(c0*t0) + invl0);
        const float ie1 = 1.0f / (1.0f/(c1*t1) + invl1);
        const float ie2 = 1.0f / (1.0f/(c2*t2));
        const float itsel = ie0 + ie1 + ie2;
        if (act && la < 2) {
            out[row*2 + la] = (la == 0) ? (ie1/itsel) : (ie0/itsel);
        }
    }
}

extern "C" void kernel_launch(void* const* d_in, const int* in_sizes, int n_in,
                              void* d_out, int out_size, void* d_ws, size_t ws_size,
                              hipStream_t stream) {
    const float* x   = (const float*)d_in[0];
    const float* W1  = (const float*)d_in[1];
    const float* b1  = (const float*)d_in[2];
    const float* W2  = (const float*)d_in[3];
    const float* b2  = (const float*)d_in[4];
    const float* W3  = (const float*)d_in[5];
    const float* b3  = (const float*)d_in[6];
    const float* W4  = (const float*)d_in[7];
    const float* b4  = (const float*)d_in[8];
    const float* kin = (const float*)d_in[9];
    float* out = (float*)d_out;
    const int B = in_sizes[0] / 5;

    // 32 rows per block (8 waves x 4 rows): B=16384 -> 512 blocks.
    // ~46 KB LDS -> 3 blocks/CU capacity; 512 blocks all resident at launch.
    const int grid = (B + WPB*4 - 1) / (WPB*4);
    ph_kernel<<<grid, BLOCK, 0, stream>>>(x, W1, b1, W2, b2, W3, b3, W4, b4, kin, out, B);
}

// Round 5
// 20.141 us; speedup vs baseline: 2.2142x; 1.0866x over previous
//
#include <hip/hip_runtime.h>
#include <math.h>

#define BLOCK 256
#define WPB 4          // waves per block
#define NGRID 1000
#define HPAD 68        // sH row stride (floats): 272B, 16B-aligned, conflict-free
#define W4S 68         // sW4t row stride

// broadcast lane i's value to all lanes (uniform SGPR result, literal index)
__device__ __forceinline__ float rdl(float v, int i) {
    return __uint_as_float(__builtin_amdgcn_readlane(__float_as_uint(v), i));
}
__device__ __forceinline__ float frcp(float x) { return __builtin_amdgcn_rcpf(x); }
__device__ __forceinline__ float fsqrt(float x) { return __builtin_amdgcn_sqrtf(x); }

__global__ __launch_bounds__(BLOCK) void ph_kernel(
    const float* __restrict__ x,
    const float* __restrict__ W1, const float* __restrict__ b1,
    const float* __restrict__ W2, const float* __restrict__ b2,
    const float* __restrict__ W3, const float* __restrict__ b3,
    const float* __restrict__ W4, const float* __restrict__ b4,
    const float* __restrict__ kin,
    float* __restrict__ out, int B)
{
    __shared__ __attribute__((aligned(16))) float sW4t[6*W4S];
    __shared__ __attribute__((aligned(16))) float sH[WPB][4][HPAD];
    __shared__ float sB4[8];
    __shared__ float sLat[WPB][4][8];

    const int tid = threadIdx.x;

    // ---- stage only W4 (tiny) into LDS, transposed, pad-68 rows ----
    for (int l = tid; l < 64*6; l += BLOCK) {
        const int i = l / 6, u = l - 6*i;
        sW4t[u*W4S + i] = W4[l];
    }
    if (tid < 8) sB4[tid] = (tid < 6) ? b4[tid] : 0.0f;
    __syncthreads();   // the only block-wide barrier

    const int lane = tid & 63;
    const int widx = tid >> 6;
    const int half = lane >> 5;
    const int la   = lane & 31;
    const int w    = blockIdx.x * WPB + widx;
    const int j    = lane;
    const int row0 = w * 4;

    // ---- weights in registers: lane j holds column j (coalesced loads) ----
    float w1r[5], w2r[64], w3r[64];
    #pragma unroll
    for (int i = 0; i < 5; ++i)  w1r[i] = W1[(i << 6) + j];
    #pragma unroll
    for (int i = 0; i < 64; ++i) w2r[i] = W2[(i << 6) + j];
    #pragma unroll
    for (int i = 0; i < 64; ++i) w3r[i] = W3[(i << 6) + j];
    const float b1j = b1[j], b2j = b2[j], b3j = b3[j];

    // ---- x for 4 rows via lanes 0..19 (clamped), distributed by readlane ----
    int xidx = row0*5 + lane;
    const int xmax = B*5 - 1;
    if (xidx > xmax) xidx = xmax;
    const float xv = x[xidx];

    // ---- layer 1: 5 -> 64, exact fma chain (i ascending, bias first) ----
    float h0 = b1j, h1 = b1j, h2 = b1j, h3 = b1j;
    #pragma unroll
    for (int i = 0; i < 5; ++i) {
        h0 = fmaf(rdl(xv, i     ), w1r[i], h0);
        h1 = fmaf(rdl(xv, 5 + i ), w1r[i], h1);
        h2 = fmaf(rdl(xv, 10 + i), w1r[i], h2);
        h3 = fmaf(rdl(xv, 15 + i), w1r[i], h3);
    }
    h0 = fmaxf(h0, 0.0f); h1 = fmaxf(h1, 0.0f);
    h2 = fmaxf(h2, 0.0f); h3 = fmaxf(h3, 0.0f);

    // ---- layer 2: 64 -> 64, zero LDS (readlane broadcast) ----
    {
        float a0 = b2j, a1 = b2j, a2 = b2j, a3 = b2j;
        #pragma unroll
        for (int i = 0; i < 64; ++i) {
            a0 = fmaf(rdl(h0, i), w2r[i], a0);
            a1 = fmaf(rdl(h1, i), w2r[i], a1);
            a2 = fmaf(rdl(h2, i), w2r[i], a2);
            a3 = fmaf(rdl(h3, i), w2r[i], a3);
        }
        h0 = fmaxf(a0, 0.0f); h1 = fmaxf(a1, 0.0f);
        h2 = fmaxf(a2, 0.0f); h3 = fmaxf(a3, 0.0f);
    }
    // ---- layer 3 ----
    {
        float a0 = b3j, a1 = b3j, a2 = b3j, a3 = b3j;
        #pragma unroll
        for (int i = 0; i < 64; ++i) {
            a0 = fmaf(rdl(h0, i), w3r[i], a0);
            a1 = fmaf(rdl(h1, i), w3r[i], a1);
            a2 = fmaf(rdl(h2, i), w3r[i], a2);
            a3 = fmaf(rdl(h3, i), w3r[i], a3);
        }
        h0 = fmaxf(a0, 0.0f); h1 = fmaxf(a1, 0.0f);
        h2 = fmaxf(a2, 0.0f); h3 = fmaxf(a3, 0.0f);
    }

    // ---- park h in LDS for layer 4 (same-wave write->read, in-order) ----
    sH[widx][0][j] = h0; sH[widx][1][j] = h1;
    sH[widx][2][j] = h2; sH[widx][3][j] = h3;

    // ---- layer 4: 64 -> 6, lanes 0..23 = (r = lane&3, u = lane>>2) ----
    if (lane < 24) {
        const int r = lane & 3, u = lane >> 2;
        const float* wrow = sW4t + u * W4S;
        const float* hrow = sH[widx][r];
        float acc = sB4[u];
        #pragma unroll
        for (int i4 = 0; i4 < 16; ++i4) {
            const float4 wv = *(const float4*)(wrow + (i4 << 2));
            const float4 hv = *(const float4*)(hrow + (i4 << 2));
            acc = fmaf(hv.x, wv.x, acc); acc = fmaf(hv.y, wv.y, acc);
            acc = fmaf(hv.z, wv.z, acc); acc = fmaf(hv.w, wv.w, acc);
        }
        sLat[widx][r][u] = acc;
    }

    const float i00 = kin[0], i01 = kin[1], i02 = kin[2];
    // ks/RT folded once (fast-math region starts here)
    const float invRT = 1.0f / 2478.8191f;
    const float ksr0 = ((-kin[3]) * 96485.33f) * invRT;
    const float ksr1 = ((-kin[4]) * 96485.33f) * invRT;
    const float ksr2 = ((-kin[5]) * 96485.33f) * invRT;
    const float stepV = 1.25f / 999.0f;

    // ---- physics: lanes {0,16,32,48} each run one row's chain ----
    float c0v = 0.0f, c1v = 0.0f, c2v = 0.0f, l0v = 0.0f, l1v = 0.0f;
    if ((lane & 15) == 0) {
        const int r = lane >> 4;
        const int row = (row0 + r < B) ? (row0 + r) : (B - 1);
        const float* plat = sLat[widx][r];
        const float lat0 = plat[0], lat1 = plat[1], lat2 = plat[2];
        const float lat3 = plat[3], lat4 = plat[4], lat5 = plat[5];
        const float rr   = 4e-8f * __expf(lat0);
        const float epsv = frcp(1.0f + __expf(-lat1));
        const float zlt  = x[row*5 + 3];
        const float Lf   = zlt * frcp(1.0f - epsv);
        const float Kdl  = __expf(lat2);
        const float z0 = 2.0f*lat3, z1 = 2.0f*lat4, z2 = 2.0f*lat5;
        const float mz = fmaxf(z0, fmaxf(z1, z2));
        const float p0 = __expf(z0 - mz), p1 = __expf(z1 - mz), p2 = __expf(z2 - mz);
        const float ips = frcp(p0 + p1 + p2);
        const float th0 = p0*ips, th1 = p1*ips, th2 = p2*ips;
        const float irr = frcp(rr);
        const float gdl   = (Kdl * 1.91e-9f) * (epsv * fsqrt(epsv)) * irr;
        const float asurf = (3.0f * (1.0f - epsv)) * Lf * irr;
        c0v = (i00*th0)*asurf; c1v = (i01*th1)*asurf; c2v = (i02*th2)*asurf;
        const float il0 = (((2.0f*96485.33f)*34.0f)*gdl)*0.1f;
        const float il1 = (((12.0f*96485.33f)*34.0f)*gdl)*0.1f;
        l0v = frcp(il0); l1v = frcp(il1);
    }

    // ---- two scan passes: pass p handles rows {2p, 2p+1} in 32-lane halves ----
    #pragma unroll
    for (int p = 0; p < 2; ++p) {
        const int r   = (p << 1) + half;
        const int row = row0 + r;
        const bool act = (row < B);
        const int src = r << 4;            // lane holding this row's constants
        const float c0    = __shfl(c0v, src, 64);
        const float c1    = __shfl(c1v, src, 64);
        const float c2    = __shfl(c2v, src, 64);
        const float invl0 = __shfl(l0v, src, 64);
        const float invl1 = __shfl(l1v, src, 64);

        auto evaltot = [&](int v) -> float {
            const float V = -1.25f + stepV * (float)v;
            const float t0 = __expf(ksr0 * (V + 0.11f));
            const float t1 = __expf(ksr1 * (V - 0.08f));
            const float t2 = __expf(ksr2 * V);
            const float ie0 = frcp(frcp(c0*t0) + invl0);
            const float ie1 = frcp(frcp(c1*t1) + invl1);
            const float ie2 = c2*t2;       // i_lim[2] = inf
            return ie0 + ie1 + ie2;
        };

        // coarse: 32 points stride 32; i_tot weakly decreasing in v
        const int vc = la << 5;            // 0..992
        const float totc = evaltot(vc);
        float bd = fabsf(totc - 200.0f);
        int bidx = vc;

        const unsigned long long mall = __ballot(totc >= 200.0f);
        const unsigned int m32 = (unsigned int)(mall >> (half << 5));
        const int kstar = m32 ? (31 - __builtin_clz(m32)) : 0;
        const int base = kstar << 5;

        // fine: 32 points (base, base+32]; coarse candidates cover the rest
        {
            int vf = base + 1 + la;
            if (vf > NGRID-1) vf = NGRID-1;
            const float totf = evaltot(vf);
            const float df = fabsf(totf - 200.0f);
            if (df < bd || (df == bd && vf < bidx)) { bd = df; bidx = vf; }
        }

        // lexicographic (d, idx) butterfly within each 32-lane half
        #pragma unroll
        for (int off = 16; off; off >>= 1) {
            const float od = __shfl_xor(bd, off, 64);
            const int   oi = __shfl_xor(bidx, off, 64);
            if (od < bd || (od == bd && oi < bidx)) { bd = od; bidx = oi; }
        }

        // ---- select + FE ----
        const float V = -1.25f + stepV * (float)bidx;
        const float t0 = __expf(ksr0 * (V + 0.11f));
        const float t1 = __expf(ksr1 * (V - 0.08f));
        const float t2 = __expf(ksr2 * V);
        const float ie0 = frcp(frcp(c0*t0) + invl0);
        const float ie1 = frcp(frcp(c1*t1) + invl1);
        const float ie2 = c2*t2;
        const float itr = frcp(ie0 + ie1 + ie2);
        if (act && la < 2) {
            out[row*2 + la] = (la == 0) ? (ie1*itr) : (ie0*itr);
        }
    }
}

extern "C" void kernel_launch(void* const* d_in, const int* in_sizes, int n_in,
                              void* d_out, int out_size, void* d_ws, size_t ws_size,
                              hipStream_t stream) {
    const float* x   = (const float*)d_in[0];
    const float* W1  = (const float*)d_in[1];
    const float* b1  = (const float*)d_in[2];
    const float* W2  = (const float*)d_in[3];
    const float* b2  = (const float*)d_in[4];
    const float* W3  = (const float*)d_in[5];
    const float* b3  = (const float*)d_in[6];
    const float* W4  = (const float*)d_in[7];
    const float* b4  = (const float*)d_in[8];
    const float* kin = (const float*)d_in[9];
    float* out = (float*)d_out;
    const int B = in_sizes[0] / 5;

    // 16 rows per block (4 waves x 4 rows): B=16384 -> 1024 blocks
    // = 4 blocks/CU resident (LDS ~7 KB, VGPR-bound), no dispatch tail.
    const int grid = (B + WPB*4 - 1) / (WPB*4);
    ph_kernel<<<grid, BLOCK, 0, stream>>>(x, W1, b1, W2, b2, W3, b3, W4, b4, kin, out, B);
}

// Round 6
// 20.072 us; speedup vs baseline: 2.2218x; 1.0035x over previous
//
#include <hip/hip_runtime.h>
#include <math.h>

#define BLOCK 256
#define WPB 4          // waves per block
#define NGRID 1000
#define HPAD 68        // sH row stride (floats): 272B, 16B-aligned
#define W4S 68         // sW4t row stride

// broadcast lane i's value to all lanes (uniform result, literal index)
__device__ __forceinline__ float rdl(float v, int i) {
    return __uint_as_float(__builtin_amdgcn_readlane(__float_as_uint(v), i));
}
__device__ __forceinline__ float frcp(float x) { return __builtin_amdgcn_rcpf(x); }
__device__ __forceinline__ float fsqrt(float x) { return __builtin_amdgcn_sqrtf(x); }

__global__ __launch_bounds__(BLOCK) void ph_kernel(
    const float* __restrict__ x,
    const float* __restrict__ W1, const float* __restrict__ b1,
    const float* __restrict__ W2, const float* __restrict__ b2,
    const float* __restrict__ W3, const float* __restrict__ b3,
    const float* __restrict__ W4, const float* __restrict__ b4,
    const float* __restrict__ kin,
    float* __restrict__ out, int B)
{
    // W2/W3 transposed + XOR-swizzled 16B granules (proven R4 layout):
    // row j (output unit) holds column j of W; granule g stored at g^(j&7).
    __shared__ __attribute__((aligned(16))) float sW2t[64*64];
    __shared__ __attribute__((aligned(16))) float sW3t[64*64];
    __shared__ __attribute__((aligned(16))) float sW4t[6*W4S];
    __shared__ __attribute__((aligned(16))) float sH[WPB][4][HPAD];
    __shared__ float sB4[8];
    __shared__ float sLat[WPB][4][8];

    const int tid = threadIdx.x;

    for (int l = tid; l < 64*64; l += BLOCK) {
        const int i = l >> 6, j = l & 63;
        const int dst = (j << 6) + ((((i >> 2) ^ (j & 7)) << 2) | (i & 3));
        sW2t[dst] = W2[l];
        sW3t[dst] = W3[l];
    }
    for (int l = tid; l < 64*6; l += BLOCK) {
        const int i = l / 6, u = l - 6*i;
        sW4t[u*W4S + i] = W4[l];
    }
    if (tid < 8) sB4[tid] = (tid < 6) ? b4[tid] : 0.0f;
    __syncthreads();   // the only block-wide barrier

    const int lane = tid & 63;
    const int widx = tid >> 6;
    const int half = lane >> 5;
    const int la   = lane & 31;
    const int w    = blockIdx.x * WPB + widx;
    const int j    = lane;
    const int row0 = w * 4;

    // small per-lane weight state (coalesced global loads, no LDS)
    float w1r[5];
    #pragma unroll
    for (int i = 0; i < 5; ++i) w1r[i] = W1[(i << 6) + j];
    const float b1j = b1[j], b2j = b2[j], b3j = b3[j];

    // x for 4 rows via lanes 0..19 (clamped), distributed by readlane
    int xidx = row0*5 + lane;
    const int xmax = B*5 - 1;
    if (xidx > xmax) xidx = xmax;
    const float xv = x[xidx];

    // ---- layer 1: 5 -> 64, exact fma chain (i ascending, bias first) ----
    float h0 = b1j, h1 = b1j, h2 = b1j, h3 = b1j;
    #pragma unroll
    for (int i = 0; i < 5; ++i) {
        h0 = fmaf(rdl(xv, i     ), w1r[i], h0);
        h1 = fmaf(rdl(xv, 5 + i ), w1r[i], h1);
        h2 = fmaf(rdl(xv, 10 + i), w1r[i], h2);
        h3 = fmaf(rdl(xv, 15 + i), w1r[i], h3);
    }
    h0 = fmaxf(h0, 0.0f); h1 = fmaxf(h1, 0.0f);
    h2 = fmaxf(h2, 0.0f); h3 = fmaxf(h3, 0.0f);

    // ---- layers 2,3: weights streamed from LDS (16 b128/layer),
    //      h broadcast via readlane (zero LDS on h path) ----
    const int swz = (j & 7) << 2;
    {
        const float* wrow = sW2t + (j << 6);
        float a0 = b2j, a1 = b2j, a2 = b2j, a3 = b2j;
        #pragma unroll
        for (int i4 = 0; i4 < 16; ++i4) {
            const float4 wv = *(const float4*)(wrow + (((i4 << 2) ^ swz)));
            const int i0 = i4 << 2;
            a0 = fmaf(rdl(h0, i0  ), wv.x, a0);
            a1 = fmaf(rdl(h1, i0  ), wv.x, a1);
            a2 = fmaf(rdl(h2, i0  ), wv.x, a2);
            a3 = fmaf(rdl(h3, i0  ), wv.x, a3);
            a0 = fmaf(rdl(h0, i0+1), wv.y, a0);
            a1 = fmaf(rdl(h1, i0+1), wv.y, a1);
            a2 = fmaf(rdl(h2, i0+1), wv.y, a2);
            a3 = fmaf(rdl(h3, i0+1), wv.y, a3);
            a0 = fmaf(rdl(h0, i0+2), wv.z, a0);
            a1 = fmaf(rdl(h1, i0+2), wv.z, a1);
            a2 = fmaf(rdl(h2, i0+2), wv.z, a2);
            a3 = fmaf(rdl(h3, i0+2), wv.z, a3);
            a0 = fmaf(rdl(h0, i0+3), wv.w, a0);
            a1 = fmaf(rdl(h1, i0+3), wv.w, a1);
            a2 = fmaf(rdl(h2, i0+3), wv.w, a2);
            a3 = fmaf(rdl(h3, i0+3), wv.w, a3);
        }
        h0 = fmaxf(a0, 0.0f); h1 = fmaxf(a1, 0.0f);
        h2 = fmaxf(a2, 0.0f); h3 = fmaxf(a3, 0.0f);
    }
    {
        const float* wrow = sW3t + (j << 6);
        float a0 = b3j, a1 = b3j, a2 = b3j, a3 = b3j;
        #pragma unroll
        for (int i4 = 0; i4 < 16; ++i4) {
            const float4 wv = *(const float4*)(wrow + (((i4 << 2) ^ swz)));
            const int i0 = i4 << 2;
            a0 = fmaf(rdl(h0, i0  ), wv.x, a0);
            a1 = fmaf(rdl(h1, i0  ), wv.x, a1);
            a2 = fmaf(rdl(h2, i0  ), wv.x, a2);
            a3 = fmaf(rdl(h3, i0  ), wv.x, a3);
            a0 = fmaf(rdl(h0, i0+1), wv.y, a0);
            a1 = fmaf(rdl(h1, i0+1), wv.y, a1);
            a2 = fmaf(rdl(h2, i0+1), wv.y, a2);
            a3 = fmaf(rdl(h3, i0+1), wv.y, a3);
            a0 = fmaf(rdl(h0, i0+2), wv.z, a0);
            a1 = fmaf(rdl(h1, i0+2), wv.z, a1);
            a2 = fmaf(rdl(h2, i0+2), wv.z, a2);
            a3 = fmaf(rdl(h3, i0+2), wv.z, a3);
            a0 = fmaf(rdl(h0, i0+3), wv.w, a0);
            a1 = fmaf(rdl(h1, i0+3), wv.w, a1);
            a2 = fmaf(rdl(h2, i0+3), wv.w, a2);
            a3 = fmaf(rdl(h3, i0+3), wv.w, a3);
        }
        h0 = fmaxf(a0, 0.0f); h1 = fmaxf(a1, 0.0f);
        h2 = fmaxf(a2, 0.0f); h3 = fmaxf(a3, 0.0f);
    }

    // ---- park h in LDS for layer 4 (same-wave write->read, in-order) ----
    sH[widx][0][j] = h0; sH[widx][1][j] = h1;
    sH[widx][2][j] = h2; sH[widx][3][j] = h3;

    // ---- layer 4: 64 -> 6, lanes 0..23 = (r = lane&3, u = lane>>2) ----
    if (lane < 24) {
        const int r = lane & 3, u = lane >> 2;
        const float* wrow = sW4t + u * W4S;
        const float* hrow = sH[widx][r];
        float acc = sB4[u];
        #pragma unroll
        for (int i4 = 0; i4 < 16; ++i4) {
            const float4 wv = *(const float4*)(wrow + (i4 << 2));
            const float4 hv = *(const float4*)(hrow + (i4 << 2));
            acc = fmaf(hv.x, wv.x, acc); acc = fmaf(hv.y, wv.y, acc);
            acc = fmaf(hv.z, wv.z, acc); acc = fmaf(hv.w, wv.w, acc);
        }
        sLat[widx][r][u] = acc;
    }

    const float i00 = kin[0], i01 = kin[1], i02 = kin[2];
    const float invRT = 1.0f / 2478.8191f;
    const float ksr0 = ((-kin[3]) * 96485.33f) * invRT;
    const float ksr1 = ((-kin[4]) * 96485.33f) * invRT;
    const float ksr2 = ((-kin[5]) * 96485.33f) * invRT;
    const float stepV = 1.25f / 999.0f;

    // ---- physics: lanes {0,16,32,48} each run one row's chain ----
    float c0v = 0.0f, c1v = 0.0f, c2v = 0.0f, l0v = 0.0f, l1v = 0.0f;
    if ((lane & 15) == 0) {
        const int r = lane >> 4;
        const int row = (row0 + r < B) ? (row0 + r) : (B - 1);
        const float* plat = sLat[widx][r];
        const float lat0 = plat[0], lat1 = plat[1], lat2 = plat[2];
        const float lat3 = plat[3], lat4 = plat[4], lat5 = plat[5];
        const float rr   = 4e-8f * __expf(lat0);
        const float epsv = frcp(1.0f + __expf(-lat1));
        const float zlt  = x[row*5 + 3];
        const float Lf   = zlt * frcp(1.0f - epsv);
        const float Kdl  = __expf(lat2);
        const float z0 = 2.0f*lat3, z1 = 2.0f*lat4, z2 = 2.0f*lat5;
        const float mz = fmaxf(z0, fmaxf(z1, z2));
        const float p0 = __expf(z0 - mz), p1 = __expf(z1 - mz), p2 = __expf(z2 - mz);
        const float ips = frcp(p0 + p1 + p2);
        const float th0 = p0*ips, th1 = p1*ips, th2 = p2*ips;
        const float irr = frcp(rr);
        const float gdl   = (Kdl * 1.91e-9f) * (epsv * fsqrt(epsv)) * irr;
        const float asurf = (3.0f * (1.0f - epsv)) * Lf * irr;
        c0v = (i00*th0)*asurf; c1v = (i01*th1)*asurf; c2v = (i02*th2)*asurf;
        const float il0 = (((2.0f*96485.33f)*34.0f)*gdl)*0.1f;
        const float il1 = (((12.0f*96485.33f)*34.0f)*gdl)*0.1f;
        l0v = frcp(il0); l1v = frcp(il1);
    }

    // ---- two scan passes: pass p handles rows {2p, 2p+1} in 32-lane halves ----
    #pragma unroll
    for (int p = 0; p < 2; ++p) {
        const int r   = (p << 1) + half;
        const int row = row0 + r;
        const bool act = (row < B);
        const int src = r << 4;            // lane holding this row's constants
        const float c0    = __shfl(c0v, src, 64);
        const float c1    = __shfl(c1v, src, 64);
        const float c2    = __shfl(c2v, src, 64);
        const float invl0 = __shfl(l0v, src, 64);
        const float invl1 = __shfl(l1v, src, 64);

        auto evaltot = [&](int v) -> float {
            const float V = -1.25f + stepV * (float)v;
            const float t0 = __expf(ksr0 * (V + 0.11f));
            const float t1 = __expf(ksr1 * (V - 0.08f));
            const float t2 = __expf(ksr2 * V);
            const float ie0 = frcp(frcp(c0*t0) + invl0);
            const float ie1 = frcp(frcp(c1*t1) + invl1);
            const float ie2 = c2*t2;       // i_lim[2] = inf
            return ie0 + ie1 + ie2;
        };

        // coarse: 32 points stride 32; i_tot weakly decreasing in v
        const int vc = la << 5;            // 0..992
        const float totc = evaltot(vc);
        float bd = fabsf(totc - 200.0f);
        int bidx = vc;

        const unsigned long long mall = __ballot(totc >= 200.0f);
        const unsigned int m32 = (unsigned int)(mall >> (half << 5));
        const int kstar = m32 ? (31 - __builtin_clz(m32)) : 0;
        const int base = kstar << 5;

        // fine: 32 points (base, base+32]; coarse candidates cover the rest
        {
            int vf = base + 1 + la;
            if (vf > NGRID-1) vf = NGRID-1;
            const float totf = evaltot(vf);
            const float df = fabsf(totf - 200.0f);
            if (df < bd || (df == bd && vf < bidx)) { bd = df; bidx = vf; }
        }

        // lexicographic (d, idx) butterfly within each 32-lane half
        #pragma unroll
        for (int off = 16; off; off >>= 1) {
            const float od = __shfl_xor(bd, off, 64);
            const int   oi = __shfl_xor(bidx, off, 64);
            if (od < bd || (od == bd && oi < bidx)) { bd = od; bidx = oi; }
        }

        // ---- select + FE ----
        const float V = -1.25f + stepV * (float)bidx;
        const float t0 = __expf(ksr0 * (V + 0.11f));
        const float t1 = __expf(ksr1 * (V - 0.08f));
        const float t2 = __expf(ksr2 * V);
        const float ie0 = frcp(frcp(c0*t0) + invl0);
        const float ie1 = frcp(frcp(c1*t1) + invl1);
        const float ie2 = c2*t2;
        const float itr = frcp(ie0 + ie1 + ie2);
        if (act && la < 2) {
            out[row*2 + la] = (la == 0) ? (ie1*itr) : (ie0*itr);
        }
    }
}

extern "C" void kernel_launch(void* const* d_in, const int* in_sizes, int n_in,
                              void* d_out, int out_size, void* d_ws, size_t ws_size,
                              hipStream_t stream) {
    const float* x   = (const float*)d_in[0];
    const float* W1  = (const float*)d_in[1];
    const float* b1  = (const float*)d_in[2];
    const float* W2  = (const float*)d_in[3];
    const float* b2  = (const float*)d_in[4];
    const float* W3  = (const float*)d_in[5];
    const float* b3  = (const float*)d_in[6];
    const float* W4  = (const float*)d_in[7];
    const float* b4  = (const float*)d_in[8];
    const float* kin = (const float*)d_in[9];
    float* out = (float*)d_out;
    const int B = in_sizes[0] / 5;

    // 16 rows per block (4 waves x 4 rows): B=16384 -> 1024 blocks
    // = 4 blocks/CU resident (~38.5 KB LDS, VGPR ~90), no dispatch tail.
    const int grid = (B + WPB*4 - 1) / (WPB*4);
    ph_kernel<<<grid, BLOCK, 0, stream>>>(x, W1, b1, W2, b2, W3, b3, W4, b4, kin, out, B);
}